// Round 10
// baseline (283.731 us; speedup 1.0000x reference)
//
#include <hip/hip_runtime.h>
#include <hip/hip_bf16.h>
#include <stdint.h>

#define S_LEN 2048
#define NHEADS 16
#define HDIM 128
#define H_TOT 2048
#define BATCH 2
#define M_TOK 4096   // B*S
#define KDIM 2048

typedef __attribute__((ext_vector_type(8))) short bf16x8;
typedef __attribute__((ext_vector_type(4))) float f32x4;
typedef __attribute__((ext_vector_type(16))) float f32x16;

__device__ inline ushort bf16rn(float f) {
  union { float f; uint32_t u; } x; x.f = f;
  uint32_t r = x.u + 0x7FFF + ((x.u >> 16) & 1);
  return (ushort)(r >> 16);
}

// ---------------- prep: f32 [rows][K] -> bf16 fragment-chunk panels ----------------
// Panel (bt, kt): ROWS x 64 cols. Chunk = 16 rows x 32 cols = 1KB, granule l=(row=l&15,
// k8=l>>4) at byte l*16 -> GEMM frag read & stage are linear-in-lane (0 bank conflicts).
// NOTE: source selection splits by 2048-row slabs (mt); for a contiguous 4096-row A,
// pass (x, x+2048*K, -) so slab 1 reads the right rows (round-9 bug: passed (x,x,x)).
//   PERM 0 (A, 16 frags):  p = ((fr>>2)&1)*8 + ((fr>>3)&1)*4 + (fr&3)
//   PERM 1 (B 256 rows):   p = ((fr>>1)&1)*8 + (fr>>2)*2 + (fr&1)
//   PERM 2 (B 128 rows):   p = (fr&1)*4 + (fr>>1)
template<int ROWS, int PERM>
__global__ __launch_bounds__(256) void prep_kernel(const float* __restrict__ p0,
                                                   const float* __restrict__ p1,
                                                   const float* __restrict__ p2,
                                                   ushort* __restrict__ out) {
  __shared__ __attribute__((aligned(16))) ushort tile[ROWS * 64];
  int kt = blockIdx.x, bt = blockIdx.y, tid = threadIdx.x;
  int mt = (bt * ROWS) >> 11;
  const float* src = (mt == 0) ? p0 : (mt == 1) ? p1 : p2;
  int rowbase = bt * ROWS - (mt << 11);
  const int IT = ROWS / 32;
#pragma unroll
  for (int i = 0; i < IT; i++) {
    int g = i * 256 + tid, row = g >> 3, k8 = g & 7;
    const float4* s4 = reinterpret_cast<const float4*>(
        src + (size_t)(rowbase + row) * KDIM + kt * 64 + k8 * 8);
    float4 a = s4[0], b = s4[1];
    union { ushort u[8]; bf16x8 v; } w;
    w.u[0] = bf16rn(a.x); w.u[1] = bf16rn(a.y); w.u[2] = bf16rn(a.z); w.u[3] = bf16rn(a.w);
    w.u[4] = bf16rn(b.x); w.u[5] = bf16rn(b.y); w.u[6] = bf16rn(b.z); w.u[7] = bf16rn(b.w);
    int fr = row >> 4;
    int p = (PERM == 0) ? (((fr >> 2) & 1) * 8 + ((fr >> 3) & 1) * 4 + (fr & 3))
          : (PERM == 1) ? (((fr >> 1) & 1) * 8 + (fr >> 2) * 2 + (fr & 1))
                        : ((fr & 1) * 4 + (fr >> 1));
    *reinterpret_cast<bf16x8*>(
        &tile[(p * 2 + (k8 >> 2)) * 512 + ((k8 & 3) * 16 + (row & 15)) * 8]) = w.v;
  }
  __syncthreads();
  ushort* op = out + ((size_t)bt * 32 + kt) * (ROWS * 64);
#pragma unroll
  for (int i = 0; i < IT; i++) {
    int g = i * 256 + tid;
    reinterpret_cast<bf16x8*>(op)[g] = reinterpret_cast<const bf16x8*>(tile)[g];
  }
}

// ---------------- gemm8: 256 x (FNW*64) tile, BK=64, 8 waves, 4-phase counted pipeline ----------------
// T3+T4 port: per phase {ds_read frag subset, issue stage half, BAR, setprio MFMA x16,
// BAR}; vmcnt gates counted (never 0 except final tail drain). All LDS accesses are
// base + lane*16 (linear-in-lane -> conflict-free). A/B panels pre-permuted so phase-p
// reads are covered by the phase-p landing guarantee:
//   P1 gate vmcnt(6/4): confirms Ah1(t);  P3 gate vmcnt(2): confirms Bh01+Ah0(t+1).
// MODE 0: fused QKV epilogue (FNW=4, N=6144); MODE 2: f32 + bias (FNW=2, N=2048).
template<int MODE, int FNW, int CHX>
__global__ __launch_bounds__(512, 2) void gemm8(const ushort* __restrict__ Apre,
                                                const ushort* __restrict__ Bpre,
                                                void* __restrict__ C0,
                                                void* __restrict__ C1,
                                                void* __restrict__ C2,
                                                const float* __restrict__ bias,
                                                float scale) {
  const int BN = FNW * 64;
  const int NLB = FNW / 2;             // loads/thread per B half (2 or 1)
  const int CHBH = BN / 16;            // chunks per B half (16 or 8)
  const int BUFB = 32768 + BN * 128;   // bytes per LDS buffer
  const int NKT = KDIM / 64;           // 32
  const int PANELA = 16384;            // ushorts per A panel
  const int PANELB = BN * 64;          // ushorts per B panel
  __shared__ __attribute__((aligned(16))) char lds[2 * (32768 + FNW * 64 * 128)];

  int tid = threadIdx.x;
  int wave = tid >> 6, lane = tid & 63;
  int lanelo = lane & 15, lanehi = lane >> 4;
  int wr = wave >> 2, wc = wave & 3;   // 2M x 4N waves; per-wave 128 x FNW*16

  int bid = blockIdx.x;
  int xcd = bid & 7, ii = bid >> 3;
  int bx = xcd * CHX + ii % CHX, by = ii / CHX;
  int bm = by * 256, bn = bx * BN;

  const ushort* pa0 = Apre + (size_t)by * NKT * PANELA;
  const ushort* pb0 = Bpre + (size_t)bx * NKT * PANELB;

#define GLD(SRC, DST)                                                                     \
  __builtin_amdgcn_global_load_lds((const __attribute__((address_space(1))) void*)(SRC),  \
                                   (__attribute__((address_space(3))) void*)(DST), 16, 0, 0)
#define STAGE_B(PB, SB)                                                                   \
  { _Pragma("unroll") for (int h_ = 0; h_ < 2; h_++)                                      \
      _Pragma("unroll") for (int j_ = 0; j_ < NLB; j_++) {                                \
        int ch_ = h_ * CHBH + j_ * 8 + wave;                                              \
        GLD((PB) + ch_ * 512 + lane * 8, (SB) + 32768 + ch_ * 1024 + lane * 16); } }
#define STAGE_A(PA, SB, H)                                                                \
  { _Pragma("unroll") for (int j_ = 0; j_ < 2; j_++) {                                    \
        int ch_ = (H) * 16 + j_ * 8 + wave;                                               \
        GLD((PA) + ch_ * 512 + lane * 8, (SB) + ch_ * 1024 + lane * 16); } }
#define READ_A(RB, MH)                                                                    \
  { _Pragma("unroll") for (int fm_ = 0; fm_ < 4; fm_++)                                   \
      _Pragma("unroll") for (int kh_ = 0; kh_ < 2; kh_++)                                 \
        afr[fm_][kh_] = *reinterpret_cast<const bf16x8*>(                                 \
            (RB) + ((((MH) * 8 + wr * 4 + fm_) * 2 + kh_) * 1024) + lane * 16); }
#define READ_B(RB, NH)                                                                    \
  { _Pragma("unroll") for (int fn_ = 0; fn_ < FNW / 2; fn_++)                             \
      _Pragma("unroll") for (int kh_ = 0; kh_ < 2; kh_++)                                 \
        bfr[(NH) * (FNW / 2) + fn_][kh_] = *reinterpret_cast<const bf16x8*>(              \
            (RB) + 32768 +                                                                \
            ((((NH) * (2 * FNW) + wc * (FNW / 2) + fn_) * 2 + kh_) * 1024) + lane * 16); }
#define MFPH(MH, NH)                                                                      \
  { __builtin_amdgcn_s_setprio(1);                                                        \
    _Pragma("unroll") for (int fm_ = 0; fm_ < 4; fm_++)                                   \
      _Pragma("unroll") for (int fn_ = 0; fn_ < FNW / 2; fn_++)                           \
        _Pragma("unroll") for (int kh_ = 0; kh_ < 2; kh_++)                               \
          acc[(MH) * 4 + fm_][(NH) * (FNW / 2) + fn_] =                                   \
              __builtin_amdgcn_mfma_f32_16x16x32_bf16(                                    \
                  afr[fm_][kh_], bfr[(NH) * (FNW / 2) + fn_][kh_],                        \
                  acc[(MH) * 4 + fm_][(NH) * (FNW / 2) + fn_], 0, 0, 0);                  \
    __builtin_amdgcn_s_setprio(0); }
#define BARR __builtin_amdgcn_s_barrier()
#define SCB __builtin_amdgcn_sched_barrier(0)

  f32x4 acc[8][FNW];
#pragma unroll
  for (int i = 0; i < 8; i++)
#pragma unroll
    for (int j = 0; j < FNW; j++) acc[i][j] = (f32x4){0.f, 0.f, 0.f, 0.f};
  bf16x8 afr[4][2], bfr[FNW][2];

  // prologue: stage tile 0 (order: Bh0,Bh1, Ah0, Ah1); confirm all but Ah1
  STAGE_B(pb0, lds);
  STAGE_A(pa0, lds, 0);
  STAGE_A(pa0, lds, 1);
  asm volatile("s_waitcnt vmcnt(2)" ::: "memory");
  SCB; BARR; SCB;

  for (int t = 0; t < NKT; t++) {
    const char* rb = lds + (t & 1) * BUFB;
    char* sb = lds + ((t + 1) & 1) * BUFB;
    const ushort* pa1 = pa0 + (size_t)(t + 1) * PANELA;
    const ushort* pb1 = pb0 + (size_t)(t + 1) * PANELB;
    bool stg = (t + 1 < NKT);
    // ---- P0 ----
    READ_A(rb, 0); READ_B(rb, 0);
    if (stg) STAGE_B(pb1, sb);
    BARR; MFPH(0, 0); BARR; SCB;
    // ---- P1 ----
    READ_B(rb, 1);
    if (stg) STAGE_A(pa1, sb, 0);
    BARR; MFPH(0, 1);
    if (stg) {
      if constexpr (FNW == 4) asm volatile("s_waitcnt vmcnt(6)" ::: "memory");
      else                    asm volatile("s_waitcnt vmcnt(4)" ::: "memory");
    } else {
      asm volatile("s_waitcnt vmcnt(0)" ::: "memory");   // tail drain
    }
    SCB; BARR; SCB;
    // ---- P2 ----
    READ_A(rb, 1);
    if (stg) STAGE_A(pa1, sb, 1);
    BARR; MFPH(1, 1); BARR; SCB;
    // ---- P3 ----
    MFPH(1, 0);
    if (stg) asm volatile("s_waitcnt vmcnt(2)" ::: "memory");
    SCB; BARR; SCB;
  }

  // ---------------- epilogue ----------------
  if (MODE == 2) {
    float* Cf = (float*)C0;
#pragma unroll
    for (int bi = 0; bi < FNW; bi++) {
      int n = bn + wc * (FNW * 16) + bi * 16 + lanelo;
      float bv = bias[n];
#pragma unroll
      for (int ai = 0; ai < 8; ai++)
#pragma unroll
        for (int q = 0; q < 4; q++) {
          int m = bm + wr * 128 + ai * 16 + lanehi * 4 + q;
          Cf[(size_t)m * H_TOT + n] = acc[ai][bi][q] + bv;
        }
    }
  } else {
    int seg = bn >> 11;
    ushort* dst = (seg == 0) ? (ushort*)C0 : (seg == 1) ? (ushort*)C1 : (ushort*)C2;
    float sc = (seg == 0) ? scale : 1.0f;
#pragma unroll
    for (int bi = 0; bi < FNW; bi++) {
      int n = (bn & 2047) + wc * (FNW * 16) + bi * 16 + lanelo;
      int h = n >> 7, d = n & 127;
#pragma unroll
      for (int ai = 0; ai < 8; ai++)
#pragma unroll
        for (int q = 0; q < 4; q++) {
          int m = bm + wr * 128 + ai * 16 + lanehi * 4 + q;
          int b = m >> 11, s = m & 2047;
          int bh = b * NHEADS + h;
          size_t idx;
          if (seg < 2) {
            idx = (((size_t)(bh * 64 + (s >> 5)) * 8 + (d >> 4)) * 64 +
                   ((d >> 3) & 1) * 32 + (s & 31)) * 8 + (d & 7);
          } else {
            int r = s & 15;
            int e = (r & 3) | ((r >> 1) & 4);
            int hi = (r >> 2) & 1;
            idx = (((size_t)(bh * 64 + (s >> 5)) * 8 + ((s >> 4) & 1) * 4 + (d >> 5)) * 64 +
                   hi * 32 + (d & 31)) * 8 + e;
          }
          dst[idx] = bf16rn(acc[ai][bi][q] * sc);
        }
    }
  }
#undef GLD
#undef STAGE_B
#undef STAGE_A
#undef READ_A
#undef READ_B
#undef MFPH
#undef BARR
#undef SCB
}

// ---------------- flash attention v5 + panel-form output epilogue ----------------
__global__ __launch_bounds__(128) void attn_kernel(const ushort* __restrict__ Qf,
                                                   const ushort* __restrict__ Kf,
                                                   const ushort* __restrict__ Vf,
                                                   ushort* __restrict__ Obpre) {
  __shared__ __attribute__((aligned(16))) ushort KV[2][8192];
  __shared__ float lsinv[2][32];
  int lane = threadIdx.x & 63, wave = threadIdx.x >> 6;
  int hi = lane >> 5;

  int bid = blockIdx.x;
  int swz = (bid & 7) * 128 + (bid >> 3);
  int bh = swz >> 5, qt = swz & 31;
  int b = bh >> 4, h = bh & 15;

  const bf16x8* Qv = reinterpret_cast<const bf16x8*>(Qf) +
                     ((size_t)(bh * 64 + qt * 2 + wave) * 8) * 64 + lane;
  bf16x8 qf[8];
#pragma unroll
  for (int kc = 0; kc < 8; kc++) qf[kc] = Qv[kc * 64];

  f32x16 oacc[4];
#pragma unroll
  for (int d32 = 0; d32 < 4; d32++)
#pragma unroll
    for (int r = 0; r < 16; r++) oacc[d32][r] = 0.f;
  float lsum = 0.f;
  int laneoff = lane * 8;
  const ushort* sbase = wave ? Vf : Kf;

#define STAGE(kt, bufsel)                                                                   \
  {                                                                                         \
    size_t gc = ((size_t)(bh * 64 + (kt))) * 8;                                             \
    _Pragma("unroll") for (int i_ = 0; i_ < 8; i_++) {                                      \
      __builtin_amdgcn_global_load_lds(                                                     \
          (const __attribute__((address_space(1))) void*)(sbase + (gc + i_) * 512 + laneoff),\
          (__attribute__((address_space(3))) void*)(&KV[bufsel][(wave * 8 + i_) * 512]),    \
          16, 0, 0);                                                                        \
    }                                                                                       \
  }

  union pu { bf16x8 v; uint32_t u[4]; };
  pu paA0, paA1, paB0, paB1;
  bf16x8 vrA[8], vrB[8];
  const bf16x8 bz = {0, 0, 0, 0, 0, 0, 0, 0};
#pragma unroll
  for (int j = 0; j < 4; j++) { paA0.u[j] = 0; paA1.u[j] = 0; }
#pragma unroll
  for (int i = 0; i < 8; i++) vrA[i] = bz;

  STAGE(0, 0);
  asm volatile("s_waitcnt vmcnt(0)" ::: "memory");
  __syncthreads();

  const int NT = S_LEN / 32;

#define BODY(T, PI0, PI1, VI, PO0, PO1, VO)                                                 \
  {                                                                                         \
    if ((T) + 1 < NT) STAGE((T) + 1, ((T) + 1) & 1);                                        \
    const ushort* lb = &KV[(T) & 1][0];                                                     \
    f32x16 S;                                                                               \
    _Pragma("unroll") for (int r = 0; r < 16; r++) S[r] = 0.f;                              \
    __builtin_amdgcn_s_setprio(1);                                                          \
    _Pragma("unroll") for (int kc = 0; kc < 8; kc++) {                                      \
      bf16x8 kfr = *reinterpret_cast<const bf16x8*>(&lb[kc * 512 + laneoff]);               \
      S = __builtin_amdgcn_mfma_f32_32x32x16_bf16(kfr, qf[kc], S, 0, 0, 0);                 \
    }                                                                                       \
    _Pragma("unroll") for (int d32 = 0; d32 < 4; d32++) {                                   \
      oacc[d32] = __builtin_amdgcn_mfma_f32_32x32x16_bf16(PI0.v, VI[d32], oacc[d32], 0, 0, 0); \
      oacc[d32] = __builtin_amdgcn_mfma_f32_32x32x16_bf16(PI1.v, VI[4 + d32], oacc[d32], 0, 0, 0); \
    }                                                                                       \
    __builtin_amdgcn_s_setprio(0);                                                          \
    float p_[16];                                                                           \
    _Pragma("unroll") for (int r = 0; r < 16; r++) { p_[r] = exp2f(S[r]); lsum += p_[r]; }  \
    _Pragma("unroll") for (int j = 0; j < 4; j++) {                                         \
      uint32_t w0_, w1_;                                                                    \
      asm("v_cvt_pk_bf16_f32 %0, %1, %2" : "=v"(w0_) : "v"(p_[2 * j]), "v"(p_[2 * j + 1])); \
      asm("v_cvt_pk_bf16_f32 %0, %1, %2" : "=v"(w1_) : "v"(p_[8 + 2 * j]), "v"(p_[9 + 2 * j])); \
      PO0.u[j] = w0_; PO1.u[j] = w1_;                                                       \
    }                                                                                       \
    _Pragma("unroll") for (int i_ = 0; i_ < 8; i_++)                                        \
      VO[i_] = *reinterpret_cast<const bf16x8*>(&lb[4096 + i_ * 512 + laneoff]);            \
    asm volatile("s_waitcnt vmcnt(0)" ::: "memory");                                        \
    __syncthreads();                                                                        \
  }

  for (int t = 0; t < NT; t += 2) {
    BODY(t,     paA0, paA1, vrA, paB0, paB1, vrB);
    BODY(t + 1, paB0, paB1, vrB, paA0, paA1, vrA);
  }
#pragma unroll
  for (int d32 = 0; d32 < 4; d32++) {
    oacc[d32] = __builtin_amdgcn_mfma_f32_32x32x16_bf16(paA0.v, vrA[d32], oacc[d32], 0, 0, 0);
    oacc[d32] = __builtin_amdgcn_mfma_f32_32x32x16_bf16(paA1.v, vrA[4 + d32], oacc[d32], 0, 0, 0);
  }

  float total = lsum + __shfl_xor(lsum, 32);
  if (lane < 32) lsinv[wave][lane] = 1.0f / total;
  __syncthreads();

  // ---- scaled O into LDS token-tile [64 rows][128 cols], then scatter panel granules ----
  ushort* ot = (ushort*)&KV[0][0];   // 16 KB, KV no longer read
#pragma unroll
  for (int d32 = 0; d32 < 4; d32++)
#pragma unroll
    for (int r = 0; r < 16; r++) {
      int row = (r & 3) + 8 * (r >> 2) + 4 * hi;
      float ls = lsinv[wave][row];
      ot[(wave * 32 + row) * 128 + d32 * 32 + (lane & 31)] = bf16rn(oacc[d32][r] * ls);
    }
  __syncthreads();
  int m0 = b * 2048 + qt * 64;
  int tid = threadIdx.x;
#pragma unroll
  for (int i = 0; i < 8; i++) {
    int g = i * 128 + tid;            // 1024 granules = 64 rows x 16 k8
    int rl = g >> 4, k8g = g & 15;
    int m = m0 + rl;
    int kcol = h * 128 + k8g * 8;
    int fm = (m & 255) >> 4;
    int pA = ((fm >> 2) & 1) * 8 + ((fm >> 3) & 1) * 4 + (fm & 3);
    size_t off = (((size_t)(m >> 8) * 32 + (kcol >> 6)) * 32 + pA * 2 + ((k8g >> 2) & 1)) * 512 +
                 (size_t)((k8g & 3) * 16 + (m & 15)) * 8;
    *reinterpret_cast<bf16x8*>(Obpre + off) = *reinterpret_cast<const bf16x8*>(ot + g * 8);
  }
#undef BODY
#undef STAGE
}

// ---------------- host-side launch ----------------
extern "C" void kernel_launch(void* const* d_in, const int* in_sizes, int n_in,
                              void* d_out, int out_size, void* d_ws, size_t ws_size,
                              hipStream_t stream) {
  const float* x  = (const float*)d_in[0];
  const float* Wq = (const float*)d_in[1];
  const float* Wk = (const float*)d_in[2];
  const float* Wv = (const float*)d_in[3];
  const float* Wo = (const float*)d_in[4];
  const float* bo = (const float*)d_in[5];
  float* out = (float*)d_out;

  char* w = (char*)d_ws;
  ushort* Apre  = (ushort*)w; w += (size_t)M_TOK * KDIM * 2;          // 16 MB
  ushort* Bpre  = (ushort*)w; w += (size_t)3 * KDIM * KDIM * 2;       // 24 MB
  ushort* WoPre = (ushort*)w; w += (size_t)KDIM * KDIM * 2;           // 8 MB
  ushort* Qh    = (ushort*)w; w += (size_t)M_TOK * KDIM * 2;
  ushort* Kh    = (ushort*)w; w += (size_t)M_TOK * KDIM * 2;
  ushort* Vt    = (ushort*)w; w += (size_t)M_TOK * KDIM * 2;
  ushort* Obpre = (ushort*)w; w += (size_t)M_TOK * KDIM * 2;

  // FIX (round-9 bug): x is one contiguous 4096-row matrix; prep splits source by
  // 2048-row slab index mt, so slab 1 must point at x + 2048*K (was x -> batch 1
  // read batch 0's activations).
  hipLaunchKernelGGL((prep_kernel<256, 0>), dim3(32, 16), dim3(256), 0, stream,
                     x, x + (size_t)2048 * KDIM, x, Apre);
  hipLaunchKernelGGL((prep_kernel<256, 1>), dim3(32, 24), dim3(256), 0, stream, Wq, Wk, Wv, Bpre);
  hipLaunchKernelGGL((prep_kernel<128, 2>), dim3(32, 16), dim3(256), 0, stream, Wo, Wo, Wo, WoPre);

  const float sl = 0.08838834764831845f * 1.4426950408889634f;  // HD^-0.5 * log2(e)

  // fused QKV: M=4096, N=6144 -> 16 x 24 tiles of 256x256 = 384 blocks
  hipLaunchKernelGGL((gemm8<0, 4, 3>), dim3(384), dim3(512), 0, stream,
                     Apre, Bpre, (void*)Qh, (void*)Kh, (void*)Vt, (const float*)nullptr, sl);

  hipLaunchKernelGGL(attn_kernel, dim3(1024), dim3(128), 0, stream, Qh, Kh, Vt, Obpre);

  // output projection: M=4096, N=2048 -> 16 x 16 tiles of 256x128 = 256 blocks
  hipLaunchKernelGGL((gemm8<2, 2, 2>), dim3(256), dim3(512), 0, stream,
                     Obpre, WoPre, (void*)out, nullptr, nullptr, bo, 1.0f);
}